// Round 5
// baseline (99.132 us; speedup 1.0000x reference)
//
#include <hip/hip_runtime.h>
#include <hip/hip_bf16.h>
#include <math.h>

#define MB 512
#define T 256
#define NP1 201
#define KNN 5

typedef unsigned long long u64;
typedef unsigned int u32;

// ---------------------------------------------------------------------------
// Fused kernel, R5. Grid = MB blocks of 512 threads (1 block = 1 batch).
// R4 post-mortem: Phase B is bounded by LDS *instruction* throughput
// (ds_read_b128 ~12cy/wave-instr; same-address lanes broadcast for free, so
// delivered-bytes was the wrong model). R5 repartitions Phase B as
// 64 rloc x 8 splits x 4 rows/thread (25 nodes per split): each node read
// serves 4 row-evals -> LDS instrs/CU halve (~8us -> ~4us). VALU/exp/sqrt
// counts and occupancy (16 waves/CU) unchanged. Split combine = 3-level
// shfl_xor. NOTE: S is now folded 8x25 instead of 4x50 -> last-ulp L drift
// (~1e-7 rel in lp). hasCust = S>0 stays exact. Phase A identical to R4
// (wave-split scan/pack + batched bit-exact 'used' fold). d_ws unused
// (2x256MiB poison fills are unconditional, ~81us of measured time).
// ---------------------------------------------------------------------------
__global__ __launch_bounds__(512, 4) void fused_kernel(
        const float* __restrict__ demands,
        const float* __restrict__ coords,
        const float* __restrict__ psi,
        const float* __restrict__ Wq_w,
        const float* __restrict__ Wq_b,
        const float* __restrict__ lam_p,
        const float* __restrict__ mu_p,
        const float* __restrict__ nu_p,
        const int* __restrict__ actions,
        const int* __restrict__ knn,
        const int* __restrict__ cap_p,
        float* __restrict__ lp_out,
        float* __restrict__ ent_out) {
    __shared__ float4 psiL[NP1];
    __shared__ float4 zCL[NP1];
    __shared__ u64   visW[4][T];   // final inclusive prefix-OR
    __shared__ float remL[T];
    __shared__ int   actL[T];
    __shared__ float demL[T];
    __shared__ u64   aggV[4][4];
    __shared__ int   aggD[4];
    __shared__ float entPart[8];

    const int b = blockIdx.x;
    const int tid = threadIdx.x;
    const int lane = tid & 63, wv = tid >> 6;

    const float cap = fmaxf((float)cap_p[0], 1e-8f);

    // ================= Phase A (wave-split) =================
    // waves 0-3: per-batch scan (thread = t).  waves 4-7: node pack.
    u64 m0 = 0, m1 = 0, m2 = 0, m3 = 0;
    int d = -1;
    if (tid < T) {
        const int t = tid;
        const int a_t = actions[b * T + t];
        actL[t] = a_t;
        demL[t] = demands[b * NP1 + a_t];

        m0 = (a_t < 64)                ? (1ull << a_t)         : 0ull;
        m1 = (a_t >= 64 && a_t < 128)  ? (1ull << (a_t - 64))  : 0ull;
        m2 = (a_t >= 128 && a_t < 192) ? (1ull << (a_t - 128)) : 0ull;
        m3 = (a_t >= 192)              ? (1ull << (a_t - 192)) : 0ull;
        d = (a_t == 0) ? t : -1;

        // wave-level inclusive scans via shfl_up (lane<off returns own)
#pragma unroll
        for (int off = 1; off < 64; off <<= 1) {
            m0 |= __shfl_up(m0, off);
            m1 |= __shfl_up(m1, off);
            m2 |= __shfl_up(m2, off);
            m3 |= __shfl_up(m3, off);
            d = max(d, __shfl_up(d, off));
        }
        if (lane == 63) {
            aggV[0][wv] = m0; aggV[1][wv] = m1;
            aggV[2][wv] = m2; aggV[3][wv] = m3;
            aggD[wv] = d;
        }
    } else {
        // pack (t-invariant per node), node = tid - 256 < 201
        const int t2 = tid - T;
        if (t2 < NP1) {
            const float lam = fminf(fmaxf(lam_p[0], -2.f), 3.f);
            const float nu  = fminf(fmaxf(nu_p[0],  -2.f), 3.f);
            const float4 pn = *(const float4*)(psi + ((size_t)b * NP1 + t2) * 4);
            const float2 cc2 = *(const float2*)(coords + ((size_t)b * NP1 + t2) * 2);
            float interf = 0.f;
            const int* kn = knn + ((size_t)b * NP1 + t2) * KNN;
#pragma unroll
            for (int k = 0; k < KNN; ++k) {
                const int j = kn[k];
                const float4 pj = *(const float4*)(psi + ((size_t)b * NP1 + j) * 4);
                interf += pn.x * pj.x + pn.y * pj.y + pn.z * pj.z + pn.w * pj.w;
            }
            const float dem = demands[b * NP1 + t2];
            float4 packC;
            packC.x = lam * interf + nu * (dem / cap);
            packC.y = cc2.x; packC.z = cc2.y; packC.w = dem;
            psiL[t2] = pn;
            zCL[t2] = packC;
        }
    }
    __syncthreads();   // barrier 1

    if (tid < T) {
        const int t = tid;
        // fold in aggregates of lower waves
        u64 p0 = 0, p1 = 0, p2 = 0, p3 = 0; int pd = -1;
        for (int u = 0; u < wv; ++u) {
            p0 |= aggV[0][u]; p1 |= aggV[1][u];
            p2 |= aggV[2][u]; p3 |= aggV[3][u];
            pd = max(pd, aggD[u]);
        }
        m0 |= p0; m1 |= p1; m2 |= p2; m3 |= p3; d = max(d, pd);
        visW[0][t] = m0; visW[1][t] = m1; visW[2][t] = m2; visW[3][t] = m3;

        // s = (last depot index <= t-1) + 1 ; d_{t-1} via shfl (lane0: aggs)
        int dPrev = __shfl_up(d, 1);
        if (lane == 0) dPrev = pd;
        const int s = dPrev + 1;     // t==0 -> pd=-1 -> s=0

        // ---- bit-exact f32 fold over [s, t), batched-load (R4) ----
        int need = t - s;
#pragma unroll
        for (int o = 1; o < 64; o <<= 1) need = max(need, __shfl_xor(need, o));

        float used = 0.f;
        for (int k0 = 0; k0 < need; k0 += 8) {
            float v[8];
#pragma unroll
            for (int u = 0; u < 8; ++u) {
                const int j = s + k0 + u;
                v[u] = demL[(j < t) ? j : 0];   // clamped in-bounds read
            }
#pragma unroll
            for (int u = 0; u < 8; ++u) {
                const int j = s + k0 + u;
                used += (j < t) ? v[u] : 0.0f;  // +0.0f is bit-exact no-op
            }
        }
        remL[t] = cap - used;
    }
    __syncthreads();   // barrier 2

    // ====== Phase B: hot loop (thread = 64 rloc x 8 splits x 4 rows) ========
    const int rloc = tid >> 3, split = tid & 7;   // rloc in [0,64)
    const float mu  = fminf(fmaxf(mu_p[0], 0.f), 20.f);

    // 25-bit vis window base for this split (base = 1 + 25*split in [1,176])
    const int base = 1 + split * 25;
    const int wsel = base >> 6;
    const int woff = base & 63;    // in {1,26,51,12,37,62,23,48} — never 0

    // per-row (c = 0..3, row tr = c*64 + rloc) context, fully unrolled
    float q0[4], q1[4], q2[4], q3[4], ccx[4], ccy[4], remA[4];
    u64 window[4];
    bool adep[4];
#pragma unroll
    for (int c = 0; c < 4; ++c) {
        const int tr = c * 64 + rloc;
        const float rem = remL[tr];
        remA[c] = rem;
        const int cur = (tr == 0) ? 0 : actL[tr - 1];
        const bool at_depot = (cur == 0);
        adep[c] = at_depot;

        u64 wlo = 0, whi = 0;
        if (tr > 0) {
            wlo = visW[wsel][tr - 1];     // depot bit shifted out (woff>=1)
            whi = (wsel < 3) ? visW[wsel + 1][tr - 1] : 0ull;
        }
        window[c] = (wlo >> woff) | (whi << (64 - woff));

        float4 pc = psiL[cur];
        if (at_depot) { pc.x = 0.f; pc.y = 0.f; pc.z = 0.f; pc.w = 0.f; }
        const float4 cz = zCL[cur];
        ccx[c] = cz.y; ccy[c] = cz.z;

        const float capn = rem / cap;
        const float tn = (float)tr / 200.f;
        const float c0 = pc.x, c1 = pc.y, c2 = pc.z, c3 = pc.w;
        q0[c] = Wq_b[0] + Wq_w[0]*c0 + Wq_w[1]*c1 + Wq_w[2]*c2 + Wq_w[3]*c3
              + Wq_w[4]*capn + Wq_w[5]*tn + Wq_w[6]*ccx[c] + Wq_w[7]*ccy[c];
        q1[c] = Wq_b[1] + Wq_w[8]*c0 + Wq_w[9]*c1 + Wq_w[10]*c2 + Wq_w[11]*c3
              + Wq_w[12]*capn + Wq_w[13]*tn + Wq_w[14]*ccx[c] + Wq_w[15]*ccy[c];
        q2[c] = Wq_b[2] + Wq_w[16]*c0 + Wq_w[17]*c1 + Wq_w[18]*c2 + Wq_w[19]*c3
              + Wq_w[20]*capn + Wq_w[21]*tn + Wq_w[22]*ccx[c] + Wq_w[23]*ccy[c];
        q3[c] = Wq_b[3] + Wq_w[24]*c0 + Wq_w[25]*c1 + Wq_w[26]*c2 + Wq_w[27]*c3
              + Wq_w[28]*capn + Wq_w[29]*tn + Wq_w[30]*ccx[c] + Wq_w[31]*ccy[c];
    }

    float S[4] = {0.f, 0.f, 0.f, 0.f};
    float W[4] = {0.f, 0.f, 0.f, 0.f};
#pragma unroll 5
    for (int i = 0; i < 25; ++i) {
        const int n = base + i;
        const float4 p4 = psiL[n];   // one b128 read reused by 4 rows
        const float4 c4 = zCL[n];
#pragma unroll
        for (int c = 0; c < 4; ++c) {
            float sco = fmaf(q0[c], p4.x, fmaf(q1[c], p4.y,
                        fmaf(q2[c], p4.z, fmaf(q3[c], p4.w, c4.x))));
            const float dx = c4.y - ccx[c], dy = c4.z - ccy[c];
            sco = fmaf(-mu, __builtin_amdgcn_sqrtf(fmaf(dx, dx, fmaf(dy, dy, 1e-12f))), sco);
            const bool maskn = (((u32)(window[c] >> i)) & 1u) || (c4.w > remA[c]);
            const float e = maskn ? 0.f : __expf(sco);
            S[c] += e;
            W[c] = fmaf(e, sco, W[c]);
        }
    }

    // combine S, W across the 8 splits — group = lane bits 2:0
#pragma unroll
    for (int c = 0; c < 4; ++c) {
        S[c] += __shfl_xor(S[c], 1); S[c] += __shfl_xor(S[c], 2);
        S[c] += __shfl_xor(S[c], 4);
        W[c] += __shfl_xor(W[c], 1); W[c] += __shfl_xor(W[c], 2);
        W[c] += __shfl_xor(W[c], 4);
    }

    float entv = 0.f;
    if (split == 0) {
        const float4 pD = psiL[0];
        const float4 zD = zCL[0];
#pragma unroll
        for (int c = 0; c < 4; ++c) {
            const int tr = c * 64 + rloc;
            // hasCust == any customer unmasked == S > 0 (e > 0 strictly)
            const bool hasCust = S[c] > 0.f;
            // depot term (n = 0): masked iff at_depot && hasCust
            {
                float sco = fmaf(q0[c], pD.x, fmaf(q1[c], pD.y,
                            fmaf(q2[c], pD.z, fmaf(q3[c], pD.w, zD.x))));
                const float dx = zD.y - ccx[c], dy = zD.z - ccy[c];
                sco = fmaf(-mu, __builtin_amdgcn_sqrtf(fmaf(dx, dx, fmaf(dy, dy, 1e-12f))), sco);
                const bool mk = adep[c] && hasCust;
                const float e = mk ? 0.f : __expf(sco);
                S[c] += e;
                W[c] = fmaf(e, sco, W[c]);
            }
            const float L = __logf(S[c]);
            const int a_row = actL[tr];
            const float4 p4 = psiL[a_row];
            const float4 c4 = zCL[a_row];
            float sco = fmaf(q0[c], p4.x, fmaf(q1[c], p4.y,
                        fmaf(q2[c], p4.z, fmaf(q3[c], p4.w, c4.x))));
            const float dx = c4.y - ccx[c], dy = c4.z - ccy[c];
            sco = fmaf(-mu, __builtin_amdgcn_sqrtf(fmaf(dx, dx, fmaf(dy, dy, 1e-12f))), sco);
            bool maskA;
            if (a_row == 0) {
                maskA = adep[c] && hasCust;
            } else {
                // bit a_row&63 of word a_row>>6; depot-bit clear only affects
                // bit 0 of word 0, never checked here (a_row >= 1)
                const u64 vw = (tr > 0) ? visW[a_row >> 6][tr - 1] : 0ull;
                maskA = ((vw >> (a_row & 63)) & 1ull) || (c4.w > remA[c]);
            }
            const float sAct = maskA ? -1e9f : sco;
            lp_out[b * T + tr] = sAct - L;
            entv += L - W[c] / S[c];
        }
    }

    // entropy: wave reduce -> block reduce -> single write (block owns batch)
#pragma unroll
    for (int o = 32; o > 0; o >>= 1) entv += __shfl_xor(entv, o);
    if (lane == 0) entPart[wv] = entv;
    __syncthreads();   // barrier 3
    if (tid == 0) {
        float tot = 0.f;
#pragma unroll
        for (int u = 0; u < 8; ++u) tot += entPart[u];
        ent_out[b] = tot * (1.f / (float)T);
    }
}

extern "C" void kernel_launch(void* const* d_in, const int* in_sizes, int n_in,
                              void* d_out, int out_size, void* d_ws, size_t ws_size,
                              hipStream_t stream) {
    const float* demands = (const float*)d_in[0];
    const float* coords  = (const float*)d_in[1];
    const float* psi     = (const float*)d_in[2];
    const float* Wq_w    = (const float*)d_in[3];
    const float* Wq_b    = (const float*)d_in[4];
    const float* lam_p   = (const float*)d_in[5];
    const float* mu_p    = (const float*)d_in[6];
    const float* nu_p    = (const float*)d_in[7];
    const int*   actions = (const int*)d_in[8];
    const int*   knn     = (const int*)d_in[9];
    const int*   cap_p   = (const int*)d_in[10];

    float* lp_out  = (float*)d_out;
    float* ent_out = lp_out + MB * T;

    // d_ws deliberately unused — R1 established the 2x 256MiB poison fills
    // (~81us) run unconditionally; they are the timed-region floor.
    (void)d_ws; (void)ws_size;

    fused_kernel<<<MB, 512, 0, stream>>>(
        demands, coords, psi, Wq_w, Wq_b, lam_p, mu_p, nu_p,
        actions, knn, cap_p, lp_out, ent_out);
}

// Round 6
// 96.655 us; speedup vs baseline: 1.0256x; 1.0256x over previous
//
#include <hip/hip_runtime.h>
#include <hip/hip_bf16.h>
#include <math.h>

#define MB 512
#define T 256
#define NP1 201
#define KNN 5

typedef unsigned long long u64;
typedef unsigned int u32;

// ---------------------------------------------------------------------------
// Fused kernel, R6 = revert to R4 (measured optimum, 97.3us).
// R5 post-mortem: 8-split x 4-row repartition regressed (+1.8us) — Phase B is
// NOT LDS-instruction-bound: trans (exp/sqrt, quarter-rate) shares the VALU
// issue port, so VALU+trans issue (~8us/CU) == LDS term (~8us/CU); cutting
// LDS frees nothing while the 4-row state (+~40 VGPR vs the 128 cap) and the
// doubled divergent epilogue cost real time. Both directions off this
// partition are now measured worse (R2/R3 coarser, R5 finer) => R4's
// 4-split x 2-row at 512 threads is the empirical optimum.
//
// Structure: grid = MB blocks of 512 threads (1 block = 1 batch).
// Phase A wave-split: waves 0-3 scan (prefix-OR visited, last-depot max,
// batched bit-exact 'used' fold), waves 4-7 knn-gather/pack.
// Phase B: 128 rloc x 4 splits x 2 rows/thread.
// d_ws unused: the 2x256MiB poison fills (~81us, 83% HBM peak) are
// unconditional harness overhead — the timed-region floor.
// ---------------------------------------------------------------------------
__global__ __launch_bounds__(512, 4) void fused_kernel(
        const float* __restrict__ demands,
        const float* __restrict__ coords,
        const float* __restrict__ psi,
        const float* __restrict__ Wq_w,
        const float* __restrict__ Wq_b,
        const float* __restrict__ lam_p,
        const float* __restrict__ mu_p,
        const float* __restrict__ nu_p,
        const int* __restrict__ actions,
        const int* __restrict__ knn,
        const int* __restrict__ cap_p,
        float* __restrict__ lp_out,
        float* __restrict__ ent_out) {
    __shared__ float4 psiL[NP1];
    __shared__ float4 zCL[NP1];
    __shared__ u64   visW[4][T];   // final inclusive prefix-OR
    __shared__ float remL[T];
    __shared__ int   actL[T];
    __shared__ float demL[T];
    __shared__ u64   aggV[4][4];
    __shared__ int   aggD[4];
    __shared__ float entPart[8];

    const int b = blockIdx.x;
    const int tid = threadIdx.x;
    const int lane = tid & 63, wv = tid >> 6;

    const float cap = fmaxf((float)cap_p[0], 1e-8f);

    // ================= Phase A (wave-split) =================
    // waves 0-3: per-batch scan (thread = t).  waves 4-7: node pack.
    u64 m0 = 0, m1 = 0, m2 = 0, m3 = 0;
    int d = -1;
    if (tid < T) {
        const int t = tid;
        const int a_t = actions[b * T + t];
        actL[t] = a_t;
        demL[t] = demands[b * NP1 + a_t];

        m0 = (a_t < 64)                ? (1ull << a_t)         : 0ull;
        m1 = (a_t >= 64 && a_t < 128)  ? (1ull << (a_t - 64))  : 0ull;
        m2 = (a_t >= 128 && a_t < 192) ? (1ull << (a_t - 128)) : 0ull;
        m3 = (a_t >= 192)              ? (1ull << (a_t - 192)) : 0ull;
        d = (a_t == 0) ? t : -1;

        // wave-level inclusive scans via shfl_up (lane<off returns own)
#pragma unroll
        for (int off = 1; off < 64; off <<= 1) {
            m0 |= __shfl_up(m0, off);
            m1 |= __shfl_up(m1, off);
            m2 |= __shfl_up(m2, off);
            m3 |= __shfl_up(m3, off);
            d = max(d, __shfl_up(d, off));
        }
        if (lane == 63) {
            aggV[0][wv] = m0; aggV[1][wv] = m1;
            aggV[2][wv] = m2; aggV[3][wv] = m3;
            aggD[wv] = d;
        }
    } else {
        // pack (t-invariant per node), node = tid - 256 < 201
        const int t2 = tid - T;
        if (t2 < NP1) {
            const float lam = fminf(fmaxf(lam_p[0], -2.f), 3.f);
            const float nu  = fminf(fmaxf(nu_p[0],  -2.f), 3.f);
            const float4 pn = *(const float4*)(psi + ((size_t)b * NP1 + t2) * 4);
            const float2 cc2 = *(const float2*)(coords + ((size_t)b * NP1 + t2) * 2);
            float interf = 0.f;
            const int* kn = knn + ((size_t)b * NP1 + t2) * KNN;
#pragma unroll
            for (int k = 0; k < KNN; ++k) {
                const int j = kn[k];
                const float4 pj = *(const float4*)(psi + ((size_t)b * NP1 + j) * 4);
                interf += pn.x * pj.x + pn.y * pj.y + pn.z * pj.z + pn.w * pj.w;
            }
            const float dem = demands[b * NP1 + t2];
            float4 packC;
            packC.x = lam * interf + nu * (dem / cap);
            packC.y = cc2.x; packC.z = cc2.y; packC.w = dem;
            psiL[t2] = pn;
            zCL[t2] = packC;
        }
    }
    __syncthreads();   // barrier 1

    if (tid < T) {
        const int t = tid;
        // fold in aggregates of lower waves
        u64 p0 = 0, p1 = 0, p2 = 0, p3 = 0; int pd = -1;
        for (int u = 0; u < wv; ++u) {
            p0 |= aggV[0][u]; p1 |= aggV[1][u];
            p2 |= aggV[2][u]; p3 |= aggV[3][u];
            pd = max(pd, aggD[u]);
        }
        m0 |= p0; m1 |= p1; m2 |= p2; m3 |= p3; d = max(d, pd);
        visW[0][t] = m0; visW[1][t] = m1; visW[2][t] = m2; visW[3][t] = m3;

        // s = (last depot index <= t-1) + 1 ; d_{t-1} via shfl (lane0: aggs)
        int dPrev = __shfl_up(d, 1);
        if (lane == 0) dPrev = pd;
        const int s = dPrev + 1;     // t==0 -> pd=-1 -> s=0

        // ---- bit-exact f32 fold over [s, t), batched-load (R4) ----
        // wave-uniform trip bound so the loop unrolls & loads batch
        int need = t - s;
#pragma unroll
        for (int o = 1; o < 64; o <<= 1) need = max(need, __shfl_xor(need, o));

        float used = 0.f;
        for (int k0 = 0; k0 < need; k0 += 8) {
            float v[8];
#pragma unroll
            for (int u = 0; u < 8; ++u) {
                const int j = s + k0 + u;
                v[u] = demL[(j < t) ? j : 0];   // clamped in-bounds read
            }
#pragma unroll
            for (int u = 0; u < 8; ++u) {
                const int j = s + k0 + u;
                used += (j < t) ? v[u] : 0.0f;  // +0.0f is bit-exact no-op
            }
        }
        remL[t] = cap - used;
    }
    __syncthreads();   // barrier 2

    // ====== Phase B: hot loop (thread = 128 rloc x 4 splits x 2 rows) =======
    const int rloc = tid >> 2, split = tid & 3;   // rloc in [0,128)
    const float mu  = fminf(fmaxf(mu_p[0], 0.f), 20.f);

    // 50-bit vis window base for this split (base in {1,51,101,151})
    const int base = 1 + split * 50;
    const int wsel = base >> 6;
    const int woff = base & 63;

    // per-row (c = 0..1, row tr = c*128 + rloc) context, fully unrolled
    float q0[2], q1[2], q2[2], q3[2], ccx[2], ccy[2], remA[2];
    u64 window[2];
    bool adep[2];
#pragma unroll
    for (int c = 0; c < 2; ++c) {
        const int tr = c * 128 + rloc;
        const float rem = remL[tr];
        remA[c] = rem;
        const int cur = (tr == 0) ? 0 : actL[tr - 1];
        const bool at_depot = (cur == 0);
        adep[c] = at_depot;

        u64 wlo = 0, whi = 0;
        if (tr > 0) {
            wlo = visW[wsel][tr - 1];     // bit 0 (depot) shifted out below
            whi = (wsel < 3) ? visW[wsel + 1][tr - 1] : 0ull;
        }
        window[c] = (wlo >> woff) | (whi << (64 - woff));  // woff >= 1 always

        float4 pc = psiL[cur];
        if (at_depot) { pc.x = 0.f; pc.y = 0.f; pc.z = 0.f; pc.w = 0.f; }
        const float4 cz = zCL[cur];
        ccx[c] = cz.y; ccy[c] = cz.z;

        const float capn = rem / cap;
        const float tn = (float)tr / 200.f;
        const float c0 = pc.x, c1 = pc.y, c2 = pc.z, c3 = pc.w;
        q0[c] = Wq_b[0] + Wq_w[0]*c0 + Wq_w[1]*c1 + Wq_w[2]*c2 + Wq_w[3]*c3
              + Wq_w[4]*capn + Wq_w[5]*tn + Wq_w[6]*ccx[c] + Wq_w[7]*ccy[c];
        q1[c] = Wq_b[1] + Wq_w[8]*c0 + Wq_w[9]*c1 + Wq_w[10]*c2 + Wq_w[11]*c3
              + Wq_w[12]*capn + Wq_w[13]*tn + Wq_w[14]*ccx[c] + Wq_w[15]*ccy[c];
        q2[c] = Wq_b[2] + Wq_w[16]*c0 + Wq_w[17]*c1 + Wq_w[18]*c2 + Wq_w[19]*c3
              + Wq_w[20]*capn + Wq_w[21]*tn + Wq_w[22]*ccx[c] + Wq_w[23]*ccy[c];
        q3[c] = Wq_b[3] + Wq_w[24]*c0 + Wq_w[25]*c1 + Wq_w[26]*c2 + Wq_w[27]*c3
              + Wq_w[28]*capn + Wq_w[29]*tn + Wq_w[30]*ccx[c] + Wq_w[31]*ccy[c];
    }

    float S[2] = {0.f, 0.f};
    float W[2] = {0.f, 0.f};
#pragma unroll 5
    for (int i = 0; i < 50; ++i) {
        const int n = base + i;
        const float4 p4 = psiL[n];   // one b128 read reused by 2 rows
        const float4 c4 = zCL[n];
#pragma unroll
        for (int c = 0; c < 2; ++c) {
            float sco = fmaf(q0[c], p4.x, fmaf(q1[c], p4.y,
                        fmaf(q2[c], p4.z, fmaf(q3[c], p4.w, c4.x))));
            const float dx = c4.y - ccx[c], dy = c4.z - ccy[c];
            sco = fmaf(-mu, __builtin_amdgcn_sqrtf(fmaf(dx, dx, fmaf(dy, dy, 1e-12f))), sco);
            const bool maskn = (((u32)(window[c] >> i)) & 1u) || (c4.w > remA[c]);
            const float e = maskn ? 0.f : __expf(sco);
            S[c] += e;
            W[c] = fmaf(e, sco, W[c]);
        }
    }

    // combine S, W across the 4 splits — quad = lane bits 1:0
#pragma unroll
    for (int c = 0; c < 2; ++c) {
        S[c] += __shfl_xor(S[c], 1); S[c] += __shfl_xor(S[c], 2);
        W[c] += __shfl_xor(W[c], 1); W[c] += __shfl_xor(W[c], 2);
    }

    float entv = 0.f;
    if (split == 0) {
        const float4 pD = psiL[0];
        const float4 zD = zCL[0];
#pragma unroll
        for (int c = 0; c < 2; ++c) {
            const int tr = c * 128 + rloc;
            // hasCust == any customer unmasked == S > 0 (e > 0 strictly)
            const bool hasCust = S[c] > 0.f;
            // depot term (n = 0): masked iff at_depot && hasCust
            {
                float sco = fmaf(q0[c], pD.x, fmaf(q1[c], pD.y,
                            fmaf(q2[c], pD.z, fmaf(q3[c], pD.w, zD.x))));
                const float dx = zD.y - ccx[c], dy = zD.z - ccy[c];
                sco = fmaf(-mu, __builtin_amdgcn_sqrtf(fmaf(dx, dx, fmaf(dy, dy, 1e-12f))), sco);
                const bool mk = adep[c] && hasCust;
                const float e = mk ? 0.f : __expf(sco);
                S[c] += e;
                W[c] = fmaf(e, sco, W[c]);
            }
            const float L = __logf(S[c]);
            const int a_row = actL[tr];
            const float4 p4 = psiL[a_row];
            const float4 c4 = zCL[a_row];
            float sco = fmaf(q0[c], p4.x, fmaf(q1[c], p4.y,
                        fmaf(q2[c], p4.z, fmaf(q3[c], p4.w, c4.x))));
            const float dx = c4.y - ccx[c], dy = c4.z - ccy[c];
            sco = fmaf(-mu, __builtin_amdgcn_sqrtf(fmaf(dx, dx, fmaf(dy, dy, 1e-12f))), sco);
            bool maskA;
            if (a_row == 0) {
                maskA = adep[c] && hasCust;
            } else {
                // bit a_row&63 of word a_row>>6; depot-bit clear only affects
                // bit 0 of word 0, never checked here (a_row >= 1)
                const u64 vw = (tr > 0) ? visW[a_row >> 6][tr - 1] : 0ull;
                maskA = ((vw >> (a_row & 63)) & 1ull) || (c4.w > remA[c]);
            }
            const float sAct = maskA ? -1e9f : sco;
            lp_out[b * T + tr] = sAct - L;
            entv += L - W[c] / S[c];
        }
    }

    // entropy: wave reduce -> block reduce -> single write (block owns batch)
#pragma unroll
    for (int o = 32; o > 0; o >>= 1) entv += __shfl_xor(entv, o);
    if (lane == 0) entPart[wv] = entv;
    __syncthreads();   // barrier 3
    if (tid == 0) {
        float tot = 0.f;
#pragma unroll
        for (int u = 0; u < 8; ++u) tot += entPart[u];
        ent_out[b] = tot * (1.f / (float)T);
    }
}

extern "C" void kernel_launch(void* const* d_in, const int* in_sizes, int n_in,
                              void* d_out, int out_size, void* d_ws, size_t ws_size,
                              hipStream_t stream) {
    const float* demands = (const float*)d_in[0];
    const float* coords  = (const float*)d_in[1];
    const float* psi     = (const float*)d_in[2];
    const float* Wq_w    = (const float*)d_in[3];
    const float* Wq_b    = (const float*)d_in[4];
    const float* lam_p   = (const float*)d_in[5];
    const float* mu_p    = (const float*)d_in[6];
    const float* nu_p    = (const float*)d_in[7];
    const int*   actions = (const int*)d_in[8];
    const int*   knn     = (const int*)d_in[9];
    const int*   cap_p   = (const int*)d_in[10];

    float* lp_out  = (float*)d_out;
    float* ent_out = lp_out + MB * T;

    // d_ws deliberately unused — R1 established the 2x 256MiB poison fills
    // (~81us) run unconditionally; they are the timed-region floor.
    (void)d_ws; (void)ws_size;

    fused_kernel<<<MB, 512, 0, stream>>>(
        demands, coords, psi, Wq_w, Wq_b, lam_p, mu_p, nu_p,
        actions, knn, cap_p, lp_out, ent_out);
}